// Round 8
// baseline (2172.749 us; speedup 1.0000x reference)
//
#include <hip/hip_runtime.h>
#include <cstdint>
#include <cstddef>

constexpr int Tn = 12, Bn = 16, Nn = 1024, Hn = 64, Ln = 2;
constexpr int ROWS = Bn * Nn;                 // 16384
constexpr int TOT  = Tn * Bn * Nn;            // 196608
constexpr int HALF = TOT / 2;
constexpr size_t HSZ = (size_t)Bn * Nn * Hn;  // 1048576 floats
constexpr size_t MB = 1048576;

#define DEVFN __device__ __forceinline__

typedef __attribute__((ext_vector_type(4))) float f32x4;
typedef __attribute__((ext_vector_type(4))) int   i32x4;
typedef __attribute__((ext_vector_type(8))) __bf16 bf16x8;
typedef unsigned short ushort_t;

// weight-plane offsets (elements) inside WH/WL (bf16 hi/lo, [n][k] layouts)
constexpr size_t WOFF_PZ = 0;        // [d][l][n:128][k:128]  gates z|r
constexpr size_t WOFF_PC = 65536;    // [d][l][n:64][k:128]   gate c
constexpr size_t WOFF_P2 = 98304;    // [n:64][k:256]         Wp2
constexpr size_t WOFF_D1 = 114688;   // [n:256][k:128]        Wd1
constexpr size_t WOFF_D2 = 147456;   // [n:64][k:256]         Wd2
constexpr size_t WTOT    = 163840;

// ---------------------------------------------------------------------------
// bf16 split helpers (RNE)
// ---------------------------------------------------------------------------
DEVFN ushort_t f2bf_rne(float f) {
  uint32_t u = __float_as_uint(f);
  uint32_t r = u + 0x7FFFu + ((u >> 16) & 1u);
  return (ushort_t)(r >> 16);
}
DEVFN float bf2f(ushort_t h) { return __uint_as_float(((uint32_t)h) << 16); }

DEVFN void split8(const float* f, bf16x8& h8, bf16x8& l8) {
  alignas(16) ushort_t hs[8], ls[8];
#pragma unroll
  for (int j = 0; j < 8; ++j) {
    ushort_t h = f2bf_rne(f[j]);
    hs[j] = h;
    ls[j] = f2bf_rne(f[j] - bf2f(h));
  }
  h8 = *reinterpret_cast<bf16x8*>(hs);
  l8 = *reinterpret_cast<bf16x8*>(ls);
}

DEVFN f32x4 mm3(bf16x8 ah, bf16x8 al, bf16x8 bh, bf16x8 bl, f32x4 c) {
  c = __builtin_amdgcn_mfma_f32_16x16x32_bf16(ah, bh, c, 0, 0, 0);
  c = __builtin_amdgcn_mfma_f32_16x16x32_bf16(ah, bl, c, 0, 0, 0);
  c = __builtin_amdgcn_mfma_f32_16x16x32_bf16(al, bh, c, 0, 0, 0);
  return c;
}

DEVFN bf16x8 ld16(const ushort_t* p) { return *reinterpret_cast<const bf16x8*>(p); }

DEVFN void ld8f(const float* p, float* out) {
  float4 v0 = *reinterpret_cast<const float4*>(p);
  float4 v1 = *reinterpret_cast<const float4*>(p + 4);
  out[0] = v0.x; out[1] = v0.y; out[2] = v0.z; out[3] = v0.w;
  out[4] = v1.x; out[5] = v1.y; out[6] = v1.z; out[7] = v1.w;
}

// async global->LDS, 16B/lane (wave-uniform base, lane auto-offset x16)
DEVFN void async16(const void* g, void* l) {
  __builtin_amdgcn_global_load_lds(
      (const __attribute__((address_space(1))) uint32_t*)g,
      (__attribute__((address_space(3))) uint32_t*)l, 16, 0, 0);
}

// i8 fixed point: v -> digits (b1,b0), scale 2^-12
DEVFN void quant_i8(float v, int& b1, int& b0) {
  int i = __float2int_rn(v * 4096.0f);
  i = max(-32768, min(32639, i));
  b1 = (i + 128) >> 8;
  b0 = i - (b1 << 8);
}

DEVFN void quantpack(const float* v, uint32_t& p1, uint32_t& p0) {
  p1 = 0; p0 = 0;
#pragma unroll
  for (int r = 0; r < 4; ++r) {
    int a, b;
    quant_i8(v[r], a, b);
    p1 |= ((uint32_t)(uint8_t)(char)a) << (8 * r);
    p0 |= ((uint32_t)(uint8_t)(char)b) << (8 * r);
  }
}

// ---------------------------------------------------------------------------
// threefry2x32 (key 0,42) + XLA-exact normal
// ---------------------------------------------------------------------------
DEVFN uint32_t rotl32(uint32_t v, int d) { return (v << d) | (v >> (32 - d)); }

DEVFN void threefry_0_42(uint32_t& x0, uint32_t& x1) {
  const uint32_t k0 = 0u, k1 = 42u, k2 = k0 ^ k1 ^ 0x1BD11BDAu;
  x0 += k0; x1 += k1;
#define TFR(r) { x0 += x1; x1 = rotl32(x1, r); x1 ^= x0; }
  TFR(13) TFR(15) TFR(26) TFR(6)
  x0 += k1; x1 += k2 + 1u;
  TFR(17) TFR(29) TFR(16) TFR(24)
  x0 += k2; x1 += k0 + 2u;
  TFR(13) TFR(15) TFR(26) TFR(6)
  x0 += k0; x1 += k1 + 3u;
  TFR(17) TFR(29) TFR(16) TFR(24)
  x0 += k1; x1 += k2 + 4u;
  TFR(13) TFR(15) TFR(26) TFR(6)
  x0 += k2; x1 += k0 + 5u;
#undef TFR
}

DEVFN float erfinv32(float x) {
  float w = -log1pf(-x * x);
  float p;
  if (w < 5.0f) {
    w = w - 2.5f;
    p = 2.81022636e-08f;
    p = fmaf(p, w, 3.43273939e-07f);
    p = fmaf(p, w, -3.5233877e-06f);
    p = fmaf(p, w, -4.39150654e-06f);
    p = fmaf(p, w, 0.00021858087f);
    p = fmaf(p, w, -0.00125372503f);
    p = fmaf(p, w, -0.00417768164f);
    p = fmaf(p, w, 0.246640727f);
    p = fmaf(p, w, 1.50140941f);
  } else {
    w = sqrtf(w) - 3.0f;
    p = -0.000200214257f;
    p = fmaf(p, w, 0.000100950558f);
    p = fmaf(p, w, 0.00134934322f);
    p = fmaf(p, w, -0.00367342844f);
    p = fmaf(p, w, 0.00573950773f);
    p = fmaf(p, w, -0.0076224613f);
    p = fmaf(p, w, 0.00943887047f);
    p = fmaf(p, w, 1.00167406f);
    p = fmaf(p, w, 2.83297682f);
  }
  return p * x;
}

DEVFN float bits_to_normal(uint32_t bits) {
  float f = __uint_as_float((bits >> 9) | 0x3f800000u) - 1.0f;
  const float lo = -0.99999994f;
  float u = fmaf(f, 2.0f, lo);
  u = fmaxf(lo, u);
  return 1.41421356237f * erfinv32(u);
}

__global__ __launch_bounds__(256) void seq_kernel(const float* __restrict__ inputs,
                                                  float* __restrict__ s0) {
  int i = blockIdx.x * 256 + threadIdx.x;
  if (i >= HALF) return;
  uint32_t x0 = (uint32_t)i, x1 = (uint32_t)(i + HALF);
  threefry_0_42(x0, x1);
  s0[i]        = inputs[i]        + 0.01f * bits_to_normal(x0);
  s0[i + HALF] = inputs[i + HALF] + 0.01f * bits_to_normal(x1);
}

DEVFN float sigmoidf_(float x) { return 1.0f / (1.0f + expf(-x)); }

// ---------------------------------------------------------------------------
// adj -> i8 digit planes (A = rn(adj*2^24); a1=(A+128)>>8; a0=A-256*a1)
// ---------------------------------------------------------------------------
__global__ __launch_bounds__(256) void adjsplit_kernel(const float* __restrict__ adj,
                                                       char* __restrict__ d1,
                                                       char* __restrict__ d0) {
  int i = blockIdx.x * 256 + threadIdx.x;
  int A = __float2int_rn(adj[i] * 16777216.0f);
  int a1 = (A + 128) >> 8;
  int a0 = A - (a1 << 8);
  d1[i] = (char)a1;
  d0[i] = (char)a0;
}

// ---------------------------------------------------------------------------
// wprep: split + transpose all GEMM B-weights into [n][k] bf16 hi/lo planes
// ---------------------------------------------------------------------------
__global__ __launch_bounds__(256) void wprep_kernel(
    const float* __restrict__ WzF, const float* __restrict__ WrF, const float* __restrict__ WcF,
    const float* __restrict__ WzR, const float* __restrict__ WrR, const float* __restrict__ WcR,
    const float* __restrict__ Wp2, const float* __restrict__ Wd1, const float* __restrict__ Wd2,
    ushort_t* __restrict__ WH, ushort_t* __restrict__ WL)
{
  size_t i = (size_t)blockIdx.x * 256 + threadIdx.x;
  if (i >= WTOT) return;
  float v;
  if (i < WOFF_PC) {                          // PZ [d][l][n:128][k:128]
    int d = (i >> 15) & 1, l = (i >> 14) & 1, n = (i >> 7) & 127, k = i & 127;
    const float* W = (n < 64) ? (d ? WzR : WzF) : (d ? WrR : WrF);
    v = W[l * 8192 + k * 64 + (n & 63)];
  } else if (i < WOFF_P2) {                   // PC [d][l][n:64][k:128]
    size_t j = i - WOFF_PC;
    int d = (j >> 14) & 1, l = (j >> 13) & 1, n = (j >> 7) & 63, k = j & 127;
    const float* W = d ? WcR : WcF;
    v = W[l * 8192 + k * 64 + n];
  } else if (i < WOFF_D1) {                   // P2 [n:64][k:256]
    size_t j = i - WOFF_P2;
    int n = j >> 8, k = j & 255;
    v = Wp2[k * 64 + n];
  } else if (i < WOFF_D2) {                   // D1 [n:256][k:128]
    size_t j = i - WOFF_D1;
    int n = j >> 7, k = j & 127;
    v = Wd1[k * 256 + n];
  } else {                                    // D2 [n:64][k:256]
    size_t j = i - WOFF_D2;
    int n = j >> 8, k = j & 255;
    v = Wd2[k * 64 + n];
  }
  ushort_t h = f2bf_rne(v);
  WH[i] = h;
  WL[i] = f2bf_rne(v - bf2f(h));
}

// ---------------------------------------------------------------------------
// proj: x = relu(s0*W0+s1*W1+bp1) @ Wp2 + bp2; emits XT digit planes
// [t][b][feat:64][m:1024] directly from C-layout regs (4-row dword packs).
// ---------------------------------------------------------------------------
__global__ __launch_bounds__(256) void proj_mfma(
    const float* __restrict__ s0g, const float* __restrict__ s1g,
    const float* __restrict__ Wp1, const float* __restrict__ bp1,
    const float* __restrict__ bp2,
    const ushort_t* __restrict__ WH, const ushort_t* __restrict__ WL,
    char* __restrict__ XT1, char* __restrict__ XT0)
{
  __shared__ float W0[256], W1[256], Bb[256], SS0[256], SS1[256];
  const int tid = threadIdx.x;
  const int row0 = blockIdx.x * 256;
  W0[tid] = Wp1[tid];
  W1[tid] = Wp1[256 + tid];
  Bb[tid] = bp1[tid];
  SS0[tid] = s0g[row0 + tid];
  SS1[tid] = s1g[row0 + tid];
  __syncthreads();

  const int lane = tid & 63, wave = tid >> 6;
  const int lm = lane & 15, q8 = (lane >> 4) * 8;
  const ushort_t* P2H = WH + WOFF_P2;
  const ushort_t* P2L = WL + WOFF_P2;

  float sv0[4], sv1[4];
#pragma unroll
  for (int ti = 0; ti < 4; ++ti) {
    sv0[ti] = SS0[wave * 64 + ti * 16 + lm];
    sv1[ti] = SS1[wave * 64 + ti * 16 + lm];
  }

  f32x4 acc[4][4];
#pragma unroll
  for (int i = 0; i < 4; ++i)
#pragma unroll
    for (int j = 0; j < 4; ++j) acc[i][j] = (f32x4)0.0f;

  for (int kt = 0; kt < 8; ++kt) {
    const int kc = kt * 32 + q8;
    bf16x8 bh[4], bl[4];
#pragma unroll
    for (int tj = 0; tj < 4; ++tj) {
      bh[tj] = ld16(P2H + (size_t)(tj * 16 + lm) * 256 + kc);
      bl[tj] = ld16(P2L + (size_t)(tj * 16 + lm) * 256 + kc);
    }
    float w08[8], w18[8], bb8[8];
#pragma unroll
    for (int j = 0; j < 8; ++j) { w08[j] = W0[kc + j]; w18[j] = W1[kc + j]; bb8[j] = Bb[kc + j]; }
#pragma unroll
    for (int ti = 0; ti < 4; ++ti) {
      float a8[8];
#pragma unroll
      for (int j = 0; j < 8; ++j)
        a8[j] = fmaxf(fmaf(sv0[ti], w08[j], fmaf(sv1[ti], w18[j], bb8[j])), 0.0f);
      bf16x8 ah, al;
      split8(a8, ah, al);
#pragma unroll
      for (int tj = 0; tj < 4; ++tj) acc[ti][tj] = mm3(ah, al, bh[tj], bl[tj], acc[ti][tj]);
    }
  }

  const int rq = (lane >> 4) * 4;
  const int rowbase = row0 + wave * 64;
#pragma unroll
  for (int ti = 0; ti < 4; ++ti)
#pragma unroll
    for (int tj = 0; tj < 4; ++tj) {
      const int col = tj * 16 + lm;
      const float bv = bp2[col];
      float v4[4];
#pragma unroll
      for (int r = 0; r < 4; ++r) v4[r] = acc[ti][tj][r] + bv;
      uint32_t p1, p0;
      quantpack(v4, p1, p0);
      const int row = rowbase + ti * 16 + rq;   // 4-aligned; same (t,b) across pack
      const int t = row >> 14, b = (row >> 10) & 15, m = row & 1023;
      const size_t adr = (size_t)t * MB + (size_t)b * 65536 + (size_t)col * 1024 + m;
      *reinterpret_cast<uint32_t*>(XT1 + adr) = p1;
      *reinterpret_cast<uint32_t*>(XT0 + adr) = p0;
    }
}

// ---------------------------------------------------------------------------
// conv_fused<PHASE>: agg = adj @ [x|h'] (i8 fixed point, K=1024 over m),
// then epilogue out = agg @ W (bf16-split MFMA) + gate nonlinearity.
// PHASE=0: W=Wzr(128 cols): z=sig(+bz) -> Z f32; r=sig(+br); rh=r*h -> RT digits
// PHASE=1: W=Wc (64 cols): c=tanh(+bc); h=z*h+(1-z)*c -> H f32 + HT digits
// Block: 64 n-rows x 128 feats, 256 thr, grid (16,16,2)=512, LDS dbuf 48 KB.
// ---------------------------------------------------------------------------
template<int PHASE>
__global__ __launch_bounds__(256) void conv_fused(
    const char* __restrict__ adj1, const char* __restrict__ adj0,
    const char* __restrict__ x0p1, const char* __restrict__ x0p0,
    const char* __restrict__ x1p1, const char* __restrict__ x1p0,
    const char* __restrict__ h0p1, const char* __restrict__ h0p0,
    const char* __restrict__ h1p1, const char* __restrict__ h1p0,
    const ushort_t* __restrict__ WH, const ushort_t* __restrict__ WL, int l,
    const float* __restrict__ b0F, const float* __restrict__ b0R,
    const float* __restrict__ b1F, const float* __restrict__ b1R,
    float* __restrict__ Z, float* __restrict__ Hbuf,
    char* __restrict__ out1, char* __restrict__ out0)
{
  constexpr int A0OFF = 4096, B1OFF = 8192, B0OFF = 16384, BUF = 24576;
  __shared__ __align__(16) char SM[2 * BUF];     // 48 KB; epilogue Tf aliases

  const int tid = threadIdx.x;
  const int n0  = blockIdx.x * 64;
  const int b   = blockIdx.y;
  const int dir = blockIdx.z;
  const char* xp1 = dir ? x1p1 : x0p1;
  const char* xp0 = dir ? x1p0 : x0p0;
  const char* hp1 = dir ? h1p1 : h0p1;
  const char* hp0 = dir ? h1p0 : h0p0;
  const int lane = tid & 63, wave = tid >> 6;
  const int sr = lane & 15, sq = lane >> 4;

  const size_t arow = (size_t)(n0 + wave * 16 + sr) * 1024 + sq * 16;
  const char* sA1 = adj1 + arow;
  const char* sA0 = adj0 + arow;
  const size_t brow = (size_t)b * 65536 + (size_t)(wave * 16 + sr) * 1024 + sq * 16;
  const char* sX1 = xp1 + brow;
  const char* sX0 = xp0 + brow;
  const char* sH1 = hp1 + brow;
  const char* sH0 = hp0 + brow;
  const int dAB = wave * 1024 + lane * 16;

  const int wr = (wave >> 1) * 32;     // n-rows within tile
  const int wc = (wave & 1) * 64;      // feat cols

  i32x4 acc1[2][4], accm[2][4];
#pragma unroll
  for (int i = 0; i < 2; ++i)
#pragma unroll
    for (int j = 0; j < 4; ++j) { acc1[i][j] = (i32x4)0; accm[i][j] = (i32x4)0; }

#define STG(bi, it)                                            \
  {                                                            \
    const int _o = (it) * 64;                                  \
    char* _L = SM + (bi) * BUF;                                \
    async16(sA1 + _o, _L + dAB);                               \
    async16(sA0 + _o, _L + A0OFF + dAB);                       \
    async16(sX1 + _o, _L + B1OFF + dAB);                       \
    async16(sH1 + _o, _L + B1OFF + 4096 + dAB);                \
    async16(sX0 + _o, _L + B0OFF + dAB);                       \
    async16(sH0 + _o, _L + B0OFF + 4096 + dAB);                \
  }

  STG(0, 0)
  for (int kt = 0; kt < 16; ++kt) {
    __syncthreads();
    if (kt + 1 < 16) STG((kt + 1) & 1, kt + 1)
    const char* L = SM + (kt & 1) * BUF;

    i32x4 bf1[4], bf0[4];
#pragma unroll
    for (int tj = 0; tj < 4; ++tj) {
      const int gb = (wave & 1) * 4 + tj;
      bf1[tj] = *reinterpret_cast<const i32x4*>(L + B1OFF + gb * 1024 + lane * 16);
      bf0[tj] = *reinterpret_cast<const i32x4*>(L + B0OFF + gb * 1024 + lane * 16);
    }
#pragma unroll
    for (int ti = 0; ti < 2; ++ti) {
      const int ga = (wave >> 1) * 2 + ti;
      i32x4 a1 = *reinterpret_cast<const i32x4*>(L + ga * 1024 + lane * 16);
      i32x4 a0 = *reinterpret_cast<const i32x4*>(L + A0OFF + ga * 1024 + lane * 16);
#pragma unroll
      for (int tj = 0; tj < 4; ++tj) {
        acc1[ti][tj] = __builtin_amdgcn_mfma_i32_16x16x64_i8(a1, bf1[tj], acc1[ti][tj], 0, 0, 0);
        accm[ti][tj] = __builtin_amdgcn_mfma_i32_16x16x64_i8(a1, bf0[tj], accm[ti][tj], 0, 0, 0);
        accm[ti][tj] = __builtin_amdgcn_mfma_i32_16x16x64_i8(a0, bf1[tj], accm[ti][tj], 0, 0, 0);
      }
    }
  }
#undef STG

  // ---------------- epilogue: out = agg @ W, then gates -------------------
  const float S1 = 0x1p-20f, Sm = 0x1p-28f;
  const int lm = lane & 15;
  const int rq4 = (lane >> 4) * 4;
  const int q8 = (lane >> 4) * 8;
  float* Tf = (float*)SM;                        // [32][132] = 16.9 KB
  constexpr int TFS = 132;
  constexpr int TJ2 = (PHASE == 0) ? 4 : 2;
  const int rowb = (wave & 1) * 16;
  const int colb = (PHASE == 0) ? (wave >> 1) * 64 : (wave >> 1) * 32;
  const ushort_t* WBH = (PHASE == 0)
      ? WH + WOFF_PZ + (size_t)(dir * 2 + l) * 16384
      : WH + WOFF_PC + (size_t)(dir * 2 + l) * 8192;
  const ushort_t* WBL = (PHASE == 0)
      ? WL + WOFF_PZ + (size_t)(dir * 2 + l) * 16384
      : WL + WOFF_PC + (size_t)(dir * 2 + l) * 8192;
  const float* bz = dir ? b0R : b0F;
  const float* br = dir ? b1R : b1F;
  float* zst = Z + (size_t)dir * ((size_t)ROWS * 64);
  float* hb = Hbuf + (size_t)(dir * 2 + l) * HSZ;
  char* o1 = (PHASE == 0) ? out1 + (size_t)dir * MB : out1 + (size_t)(dir * 2 + l) * MB;
  char* o0 = (PHASE == 0) ? out0 + (size_t)dir * MB : out0 + (size_t)(dir * 2 + l) * MB;

  for (int h2 = 0; h2 < 2; ++h2) {
    __syncthreads();
    if ((wave >> 1) == h2) {
#pragma unroll
      for (int ti = 0; ti < 2; ++ti)
#pragma unroll
        for (int tj = 0; tj < 4; ++tj) {
          const int c = wc + tj * 16 + lm;
#pragma unroll
          for (int r = 0; r < 4; ++r)
            Tf[(ti * 16 + rq4 + r) * TFS + c] =
                (float)acc1[ti][tj][r] * S1 + (float)accm[ti][tj][r] * Sm;
        }
    }
    __syncthreads();

    f32x4 a2[TJ2];
#pragma unroll
    for (int j = 0; j < TJ2; ++j) a2[j] = (f32x4)0.0f;
#pragma unroll
    for (int kt2 = 0; kt2 < 4; ++kt2) {
      const int k0 = kt2 * 32 + q8;
      bf16x8 wh[TJ2], wl[TJ2];
#pragma unroll
      for (int j = 0; j < TJ2; ++j) {
        const int g = colb + j * 16 + lm;
        wh[j] = ld16(WBH + (size_t)g * 128 + k0);
        wl[j] = ld16(WBL + (size_t)g * 128 + k0);
      }
      float a8[8];
      ld8f(&Tf[(rowb + lm) * TFS + k0], a8);
      bf16x8 ah, al;
      split8(a8, ah, al);
#pragma unroll
      for (int j = 0; j < TJ2; ++j) a2[j] = mm3(ah, al, wh[j], wl[j], a2[j]);
    }

    const size_t grow0 = (size_t)b * 1024 + n0 + h2 * 32 + rowb + rq4;
    const int m0 = n0 + h2 * 32 + rowb + rq4;
    if (PHASE == 0) {
      if (colb == 0) {                 // z gate (waves 0,1)
#pragma unroll
        for (int j = 0; j < TJ2; ++j) {
          const int g = j * 16 + lm;
          const float bv = bz[g];
#pragma unroll
          for (int r = 0; r < 4; ++r)
            zst[(grow0 + r) * 64 + g] = sigmoidf_(a2[j][r] + bv);
        }
      } else {                         // r gate -> rh digits (waves 2,3)
#pragma unroll
        for (int j = 0; j < TJ2; ++j) {
          const int c = j * 16 + lm;
          const float bv = br[c];
          float rv[4];
#pragma unroll
          for (int r = 0; r < 4; ++r)
            rv[r] = sigmoidf_(a2[j][r] + bv) * hb[(grow0 + r) * 64 + c];
          uint32_t p1, p0;
          quantpack(rv, p1, p0);
          const size_t adr = (size_t)b * 65536 + (size_t)c * 1024 + m0;
          *reinterpret_cast<uint32_t*>(o1 + adr) = p1;
          *reinterpret_cast<uint32_t*>(o0 + adr) = p0;
        }
      }
    } else {
#pragma unroll
      for (int j = 0; j < TJ2; ++j) {
        const int g = colb + j * 16 + lm;
        const float bv = bz[g];        // bc
        float hv4[4];
#pragma unroll
        for (int r = 0; r < 4; ++r) {
          const size_t idx = (grow0 + r) * 64 + g;
          const float cc = tanhf(a2[j][r] + bv);
          const float zv = zst[idx];
          const float hn = zv * hb[idx] + (1.0f - zv) * cc;
          hb[idx] = hn;
          hv4[r] = hn;
        }
        uint32_t p1, p0;
        quantpack(hv4, p1, p0);
        const size_t adr = (size_t)b * 65536 + (size_t)g * 1024 + m0;
        *reinterpret_cast<uint32_t*>(o1 + adr) = p1;
        *reinterpret_cast<uint32_t*>(o0 + adr) = p0;
      }
    }
  }
}

// ---------------------------------------------------------------------------
// dec1: D1[row][256] = relu(concat(hid_f,hid_r)[row] @ Wd1 + bd1)
// ---------------------------------------------------------------------------
__global__ __launch_bounds__(256) void dec1_mfma(
    const float* __restrict__ Hws,
    const ushort_t* __restrict__ WH, const ushort_t* __restrict__ WL,
    const float* __restrict__ bd1,
    float* __restrict__ D1)
{
  const int tid = threadIdx.x;
  const int row0 = blockIdx.x * 128;
  const int cb   = blockIdx.y * 128;
  const int l  = row0 >> 14;
  const int ri0 = row0 & 16383;
  const float* Hf = Hws + (size_t)l * HSZ;
  const float* Hr = Hws + (size_t)(2 + l) * HSZ;
  const ushort_t* BH = WH + WOFF_D1;
  const ushort_t* BL = WL + WOFF_D1;

  const int lane = tid & 63, wave = tid >> 6;
  const int wr = (wave >> 1) * 64, wc = (wave & 1) * 64;
  const int lm = lane & 15, q8 = (lane >> 4) * 8;

  f32x4 acc[4][4];
#pragma unroll
  for (int i = 0; i < 4; ++i)
#pragma unroll
    for (int j = 0; j < 4; ++j) acc[i][j] = (f32x4)0.0f;

#pragma unroll
  for (int kt = 0; kt < 4; ++kt) {
    const int k0 = kt * 32 + q8;
    bf16x8 bh[4], bl[4];
#pragma unroll
    for (int tj = 0; tj < 4; ++tj) {
      const size_t off = (size_t)(cb + wc + tj * 16 + lm) * 128 + k0;
      bh[tj] = ld16(BH + off);
      bl[tj] = ld16(BL + off);
    }
#pragma unroll
    for (int ti = 0; ti < 4; ++ti) {
      const int ri = ri0 + wr + ti * 16 + lm;
      const float* src = (k0 < 64) ? (Hf + (size_t)ri * 64 + k0)
                                   : (Hr + (size_t)ri * 64 + (k0 - 64));
      float a8[8];
      ld8f(src, a8);
      bf16x8 ah, al;
      split8(a8, ah, al);
#pragma unroll
      for (int tj = 0; tj < 4; ++tj) acc[ti][tj] = mm3(ah, al, bh[tj], bl[tj], acc[ti][tj]);
    }
  }

  const int rq = (lane >> 4) * 4;
#pragma unroll
  for (int ti = 0; ti < 4; ++ti)
#pragma unroll
    for (int tj = 0; tj < 4; ++tj) {
      const int col = cb + wc + tj * 16 + lm;
      const float bv = bd1[col];
#pragma unroll
      for (int r = 0; r < 4; ++r) {
        const size_t row = row0 + wr + ti * 16 + rq + r;
        D1[row * 256 + col] = fmaxf(acc[ti][tj][r] + bv, 0.0f);
      }
    }
}

// ---------------------------------------------------------------------------
// dec2: out[row][64] = D1[row] @ Wd2 + bd2
// ---------------------------------------------------------------------------
__global__ __launch_bounds__(256) void dec2_mfma(
    const float* __restrict__ D1,
    const ushort_t* __restrict__ WH, const ushort_t* __restrict__ WL,
    const float* __restrict__ bd2,
    float* __restrict__ out)
{
  const int tid = threadIdx.x;
  const int row0 = blockIdx.x * 256;
  const ushort_t* BH = WH + WOFF_D2;
  const ushort_t* BL = WL + WOFF_D2;

  const int lane = tid & 63, wave = tid >> 6;
  const int wr = wave * 64;
  const int lm = lane & 15, q8 = (lane >> 4) * 8;

  f32x4 acc[4][4];
#pragma unroll
  for (int i = 0; i < 4; ++i)
#pragma unroll
    for (int j = 0; j < 4; ++j) acc[i][j] = (f32x4)0.0f;

#pragma unroll
  for (int kt = 0; kt < 8; ++kt) {
    const int k0 = kt * 32 + q8;
    bf16x8 bh[4], bl[4];
#pragma unroll
    for (int tj = 0; tj < 4; ++tj) {
      const size_t off = (size_t)(tj * 16 + lm) * 256 + k0;
      bh[tj] = ld16(BH + off);
      bl[tj] = ld16(BL + off);
    }
#pragma unroll
    for (int ti = 0; ti < 4; ++ti) {
      const size_t row = row0 + wr + ti * 16 + lm;
      float a8[8];
      ld8f(D1 + row * 256 + k0, a8);
      bf16x8 ah, al;
      split8(a8, ah, al);
#pragma unroll
      for (int tj = 0; tj < 4; ++tj) acc[ti][tj] = mm3(ah, al, bh[tj], bl[tj], acc[ti][tj]);
    }
  }

  const int rq = (lane >> 4) * 4;
#pragma unroll
  for (int ti = 0; ti < 4; ++ti)
#pragma unroll
    for (int tj = 0; tj < 4; ++tj) {
      const int col = tj * 16 + lm;
      const float bv = bd2[col];
#pragma unroll
      for (int r = 0; r < 4; ++r) {
        const size_t row = row0 + wr + ti * 16 + rq + r;
        out[row * 64 + col] = acc[ti][tj][r] + bv;
      }
    }
}

// ---------------------------------------------------------------------------
// Host driver
// ---------------------------------------------------------------------------
extern "C" void kernel_launch(void* const* d_in, const int* in_sizes, int n_in,
                              void* d_out, int out_size, void* d_ws, size_t ws_size,
                              hipStream_t stream)
{
  (void)in_sizes; (void)n_in; (void)out_size; (void)ws_size;
  const float* inputs = (const float*)d_in[0];
  const float* mask   = (const float*)d_in[1];
  const float* adj    = (const float*)d_in[2];
  const float* Wp1    = (const float*)d_in[3];
  const float* bp1    = (const float*)d_in[4];
  const float* Wp2    = (const float*)d_in[5];
  const float* bp2    = (const float*)d_in[6];
  const float* Wz_f   = (const float*)d_in[7];
  const float* Wr_f   = (const float*)d_in[8];
  const float* Wc_f   = (const float*)d_in[9];
  const float* bz_f   = (const float*)d_in[10];
  const float* br_f   = (const float*)d_in[11];
  const float* bc_f   = (const float*)d_in[12];
  const float* Wz_r   = (const float*)d_in[13];
  const float* Wr_r   = (const float*)d_in[14];
  const float* Wc_r   = (const float*)d_in[15];
  const float* bz_r   = (const float*)d_in[16];
  const float* br_r   = (const float*)d_in[17];
  const float* bc_r   = (const float*)d_in[18];
  const float* Wd1    = (const float*)d_in[19];
  const float* bd1    = (const float*)d_in[20];
  const float* Wd2    = (const float*)d_in[21];
  const float* bd2    = (const float*)d_in[22];

  float* ws = (float*)d_ws;
  float* S0 = ws;                                   // TOT
  float* H  = S0 + TOT;                             // 4*HSZ [dir*2+l]
  float* Z  = H + 4 * HSZ;                          // 2*HSZ
  char* ADJ1 = (char*)(Z + 2 * HSZ);                // 1 MB
  char* ADJ0 = ADJ1 + MB;                           // 1 MB
  ushort_t* WH = (ushort_t*)(ADJ0 + MB);
  ushort_t* WL = WH + WTOT;
  char* XT1 = (char*)(WL + WTOT);                   // 12 MB [t][b][64][1024]
  char* XT0 = XT1 + 12 * MB;                        // 12 MB
  char* HT1 = XT0 + 12 * MB;                        // 4 MB  [dir*2+l][b][64][1024]
  char* HT0 = HT1 + 4 * MB;                         // 4 MB
  char* RT1 = HT0 + 4 * MB;                         // 2 MB  [dir][b][64][1024]
  char* RT0 = RT1 + 2 * MB;                         // 2 MB
  float* D1 = (float*)XT1;                          // 32 MB alias (post-loop)

  hipMemsetAsync(H, 0, 4 * HSZ * sizeof(float), stream);
  hipMemsetAsync(HT1, 0, 8 * MB, stream);           // HT1+HT0 contiguous

  seq_kernel<<<dim3((HALF + 255) / 256), 256, 0, stream>>>(inputs, S0);
  wprep_kernel<<<dim3((WTOT + 255) / 256), 256, 0, stream>>>(
      Wz_f, Wr_f, Wc_f, Wz_r, Wr_r, Wc_r, Wp2, Wd1, Wd2, WH, WL);
  adjsplit_kernel<<<dim3(4096), 256, 0, stream>>>(adj, ADJ1, ADJ0);
  proj_mfma<<<dim3(TOT / 256), 256, 0, stream>>>(S0, mask, Wp1, bp1, bp2, WH, WL, XT1, XT0);

  for (int t = 0; t < Tn; ++t) {
    for (int l = 0; l < Ln; ++l) {
      // x planes per dir (digit1/digit0)
      const char* x01 = (l == 0) ? XT1 + (size_t)t * MB        : HT1 + 0 * MB;  // dir0: l0 plane 0
      const char* x00 = (l == 0) ? XT0 + (size_t)t * MB        : HT0 + 0 * MB;
      const char* x11 = (l == 0) ? XT1 + (size_t)(11 - t) * MB : HT1 + 2 * MB;  // dir1: l0 plane 2
      const char* x10 = (l == 0) ? XT0 + (size_t)(11 - t) * MB : HT0 + 2 * MB;

      conv_fused<0><<<dim3(16, 16, 2), 256, 0, stream>>>(
          ADJ1, ADJ0, x01, x00, x11, x10,
          HT1 + (size_t)(0 * 2 + l) * MB, HT0 + (size_t)(0 * 2 + l) * MB,
          HT1 + (size_t)(1 * 2 + l) * MB, HT0 + (size_t)(1 * 2 + l) * MB,
          WH, WL, l,
          bz_f + l * 64, bz_r + l * 64, br_f + l * 64, br_r + l * 64,
          Z, H, RT1, RT0);

      conv_fused<1><<<dim3(16, 16, 2), 256, 0, stream>>>(
          ADJ1, ADJ0, x01, x00, x11, x10,
          RT1, RT0, RT1 + MB, RT0 + MB,
          WH, WL, l,
          bc_f + l * 64, bc_r + l * 64, bc_f + l * 64, bc_r + l * 64,
          Z, H, HT1, HT0);
    }
  }

  dec1_mfma<<<dim3(256, 2), 256, 0, stream>>>(H, WH, WL, bd1, D1);
  dec2_mfma<<<dim3(128), 256, 0, stream>>>(D1, WH, WL, bd2, (float*)d_out);
}